// Round 1
// baseline (16536.787 us; speedup 1.0000x reference)
//
#include <hip/hip_runtime.h>
#include <math.h>

#define BATCH 4
#define MMDIM 256
#define NNDIM 256
#define CH 64
#define NMODES 32
#define HID 128
#define NLAYERS 4

// ---------------- setup kernels ----------------

// T[k][n] = cos(pi*(n+0.5)*k/256)*sqrt(2/256), row 0 scaled by 1/sqrt(2).
// Only the first 32 rows of the DCT matrix are ever used by the reference
// (truncation to MODES happens before any other use), and M==N so one table.
__global__ __launch_bounds__(256) void k_build_T(float* __restrict__ T) {
    int k = blockIdx.x, n = threadIdx.x;
    double v = cos(M_PI * (n + 0.5) * (double)k / 256.0) * sqrt(2.0 / 256.0);
    if (k == 0) v *= 0.7071067811865476;
    T[k * 256 + n] = (float)v;
}

// fw: [L][64][64][32] (l,i,o,y)  ->  wt: [L][32][64][64] (l,y,i,o)
__global__ __launch_bounds__(256) void k_wt(const float* __restrict__ fw, float* __restrict__ wt) {
    int idx = blockIdx.x * 256 + threadIdx.x;   // over L*32*64*64 = 524288
    int l = idx >> 17, r = idx & 131071;
    int y = r >> 12, i = (r >> 6) & 63, o = r & 63;
    wt[idx] = fw[((l * 64 + i) * 64 + o) * 32 + y];
}

// Fuse the two head matmuls: W_eff[c] = sum_j W_o2[j]*W_o1[j][c]; b_eff = W_o2.b_o1 + b_o2
__global__ void k_head(const float* __restrict__ W_o1, const float* __restrict__ b_o1,
                       const float* __restrict__ W_o2, const float* __restrict__ b_o2,
                       float* __restrict__ Weff, float* __restrict__ beff) {
    int c = threadIdx.x;  // 64
    float acc = 0.f;
    for (int j = 0; j < 128; j++) acc += W_o2[j] * W_o1[j * 64 + c];
    Weff[c] = acc;
    if (c == 0) {
        float bb = 0.f;
        for (int j = 0; j < 128; j++) bb += W_o2[j] * b_o1[j];
        beff[0] = bb + b_o2[0];
    }
}

// x64[p][c] = sum_d xin[p][d]*W_in[c][d] + b_in[c]   (4 pixels per 256-thread block)
__global__ __launch_bounds__(256) void k_inproj(const float* __restrict__ xin,
                                                const float* __restrict__ W_in,
                                                const float* __restrict__ b_in,
                                                float* __restrict__ x64) {
    int t = threadIdx.x;
    long p = (long)blockIdx.x * 4 + (t >> 6);
    int c = t & 63;
    const float* xr = xin + p * 12;
    float acc = b_in[c];
#pragma unroll
    for (int d = 0; d < 12; d++) acc += xr[d] * W_in[c * 12 + d];
    x64[p * 64 + c] = acc;
}

// ---------------- per-layer kernels ----------------

// Forward DCT along one axis, keep 32 modes.
// Block = one (b, f) slab. Stages the 256x64 slab in LDS, each thread computes
// 8 (y,c) outputs. X layout: [b*256+f][32][64] = (b,f,y,c).
__global__ __launch_bounds__(256) void k_dct(const float* __restrict__ x, const float* __restrict__ T,
                                             float* __restrict__ X, long strideA, long strideF) {
    __shared__ float lds[256 * 64];   // 64 KiB
    int t = threadIdx.x;
    int b = blockIdx.x >> 8, f = blockIdx.x & 255;
    const float* base = x + (long)b * (256L * 256 * 64) + (long)f * strideF;
    int c = t & 63, grp = t >> 6;

    if (strideA == 64) {  // contiguous slab: vectorized load
        const float4* src = (const float4*)base;
        float4* dst = (float4*)lds;
        for (int k = t; k < 4096; k += 256) dst[k] = src[k];
    } else {
        for (int a0 = 0; a0 < 256; a0 += 4) {
            int a = a0 + grp;
            lds[a * 64 + c] = base[(long)a * strideA + c];
        }
    }
    __syncthreads();

    float acc[8];
#pragma unroll
    for (int i = 0; i < 8; i++) acc[i] = 0.f;
    int ybase = grp * 8;
#pragma unroll 2
    for (int a = 0; a < 256; a++) {
        float xv = lds[a * 64 + c];
#pragma unroll
        for (int i = 0; i < 8; i++) acc[i] += xv * T[(ybase + i) * 256 + a];
    }
    float* outp = X + ((long)blockIdx.x * 32 + ybase) * 64 + c;
#pragma unroll
    for (int i = 0; i < 8; i++) outp[i * 64] = acc[i];
}

// Channel mix per mode: Xm[bf][y][o] = sum_i X[bf][y][i] * wt[y][i][o]
__global__ __launch_bounds__(256) void k_mix(const float* __restrict__ X,
                                             const float* __restrict__ wt,
                                             float* __restrict__ Xm) {
    __shared__ float lds[32 * 64];
    int t = threadIdx.x;
    const float* base = X + (long)blockIdx.x * 2048;
    for (int k = t; k < 2048; k += 256) lds[k] = base[k];
    __syncthreads();
    int o = t & 63, grp = t >> 6;
    float* outp = Xm + (long)blockIdx.x * 2048;
    for (int yy = 0; yy < 8; yy++) {
        int y = grp * 8 + yy;
        const float* w = wt + (long)y * 4096 + o;
        const float* xr = lds + y * 64;
        float acc = 0.f;
#pragma unroll 16
        for (int i = 0; i < 64; i++) acc += xr[i] * w[i * 64];
        outp[y * 64 + o] = acc;
    }
}

// Inverse transform: h[b, a, f (or f, a), o] (+)= sum_y Xm[bf][y][o]*T[y][a]
__global__ __launch_bounds__(256) void k_idct(const float* __restrict__ Xm, const float* __restrict__ T,
                                              float* __restrict__ h, long strideA, long strideF, int accum) {
    __shared__ float lds[32 * 64];
    int t = threadIdx.x;
    int b = blockIdx.x >> 8, f = blockIdx.x & 255;
    const float* base = Xm + (long)blockIdx.x * 2048;
    for (int k = t; k < 2048; k += 256) lds[k] = base[k];
    __syncthreads();
    int o = t & 63, grp = t >> 6;
    float* outp = h + (long)b * (256L * 256 * 64) + (long)f * strideF;
    for (int aa = 0; aa < 64; aa++) {
        int a = grp * 64 + aa;
        float acc = 0.f;
#pragma unroll
        for (int y = 0; y < 32; y++) acc += lds[y * 64 + o] * T[y * 256 + a];
        long off = (long)a * strideA + o;
        if (accum) outp[off] += acc;
        else outp[off] = acc;
    }
}

// Fused FFN + residual (+ fused head on the last layer).
// 128 threads = 128 pixels per block; weights stream through the scalar path
// (j,c loops are wave-uniform), h/x staged through LDS for coalescing.
__global__ __launch_bounds__(128) void k_ff(const float* __restrict__ h, float* __restrict__ x,
                                            const float* __restrict__ W1, const float* __restrict__ b1,
                                            const float* __restrict__ W2, const float* __restrict__ b2,
                                            const float* __restrict__ Weff, const float* __restrict__ beff,
                                            float* __restrict__ out, int last) {
    __shared__ float lds[128 * 65];
    int t = threadIdx.x;
    long p0 = (long)blockIdx.x * 128;
    const float* hb = h + p0 * 64;
    for (int k = t; k < 8192; k += 128) lds[(k >> 6) * 65 + (k & 63)] = hb[k];
    __syncthreads();

    float hr[64];
#pragma unroll
    for (int c = 0; c < 64; c++) hr[c] = lds[t * 65 + c];
    float oacc[64];
#pragma unroll
    for (int c = 0; c < 64; c++) oacc[c] = 0.f;

    for (int j = 0; j < 128; j++) {
        const float* w1r = W1 + j * 64;
        float a = b1[j];
#pragma unroll 16
        for (int c = 0; c < 64; c++) a += hr[c] * w1r[c];
        a = fmaxf(a, 0.f);
        const float* w2c = W2 + j;  // W2[c][j], stride 128
#pragma unroll 16
        for (int c = 0; c < 64; c++) oacc[c] += a * w2c[c * 128];
    }

    if (last) {
        float acc = beff[0];
#pragma unroll 16
        for (int c = 0; c < 64; c++) acc += (oacc[c] + b2[c]) * Weff[c];
        out[p0 + t] = acc;
    } else {
        __syncthreads();  // done reading h from lds
#pragma unroll
        for (int c = 0; c < 64; c++) lds[t * 65 + c] = oacc[c] + b2[c];
        __syncthreads();
        float* xb = x + p0 * 64;
        for (int k = t; k < 8192; k += 128) xb[k] += lds[(k >> 6) * 65 + (k & 63)];
    }
}

// ---------------- launcher ----------------

extern "C" void kernel_launch(void* const* d_in, const int* in_sizes, int n_in,
                              void* d_out, int out_size, void* d_ws, size_t ws_size,
                              hipStream_t stream) {
    const float* x_in = (const float*)d_in[0];
    const float* W_in = (const float*)d_in[1];
    const float* b_in = (const float*)d_in[2];
    const float* fw0  = (const float*)d_in[3];
    const float* fw1  = (const float*)d_in[4];
    const float* ffW1 = (const float*)d_in[5];
    const float* ffb1 = (const float*)d_in[6];
    const float* ffW2 = (const float*)d_in[7];
    const float* ffb2 = (const float*)d_in[8];
    const float* W_o1 = (const float*)d_in[9];
    const float* b_o1 = (const float*)d_in[10];
    const float* W_o2 = (const float*)d_in[11];
    const float* b_o2 = (const float*)d_in[12];
    float* out = (float*)d_out;

    // workspace layout (floats). Total ~155 MB.
    float* ws   = (float*)d_ws;
    float* T    = ws;                                   // 32*256      = 8192
    float* w0t  = T + 8192;                             // 4*32*64*64  = 524288
    float* w1t  = w0t + (long)NLAYERS * NMODES * CH * CH;
    float* Weff = w1t + (long)NLAYERS * NMODES * CH * CH;  // 64
    float* beff = Weff + 64;                            // 1 (+pad)
    float* x64  = beff + 64;                            // 4*256*256*64 = 16777216
    float* h    = x64 + (long)BATCH * MMDIM * NNDIM * CH;
    float* A    = h + (long)BATCH * MMDIM * NNDIM * CH; // 4*256*32*64 = 2097152
    float* Am   = A + (long)BATCH * MMDIM * NMODES * CH;

    k_build_T<<<32, 256, 0, stream>>>(T);
    k_wt<<<2048, 256, 0, stream>>>(fw0, w0t);
    k_wt<<<2048, 256, 0, stream>>>(fw1, w1t);
    k_head<<<1, 64, 0, stream>>>(W_o1, b_o1, W_o2, b_o2, Weff, beff);
    k_inproj<<<65536, 256, 0, stream>>>(x_in, W_in, b_in, x64);

    for (int l = 0; l < NLAYERS; l++) {
        // y-path: DCT along n (contiguous), mix with w0, inverse, write h
        k_dct<<<1024, 256, 0, stream>>>(x64, T, A, 64L, 16384L);
        k_mix<<<1024, 256, 0, stream>>>(A, w0t + (long)l * NMODES * CH * CH, Am);
        k_idct<<<1024, 256, 0, stream>>>(Am, T, h, 64L, 16384L, 0);
        // x-path: DCT along m (strided), mix with w1, inverse, accumulate into h
        k_dct<<<1024, 256, 0, stream>>>(x64, T, A, 16384L, 64L);
        k_mix<<<1024, 256, 0, stream>>>(A, w1t + (long)l * NMODES * CH * CH, Am);
        k_idct<<<1024, 256, 0, stream>>>(Am, T, h, 16384L, 64L, 1);
        // fused FFN + residual (+ head on last layer)
        k_ff<<<2048, 128, 0, stream>>>(h, x64,
            ffW1 + (long)l * HID * CH, ffb1 + (long)l * HID,
            ffW2 + (long)l * CH * HID, ffb2 + (long)l * CH,
            Weff, beff, out, (l == NLAYERS - 1) ? 1 : 0);
    }
}

// Round 2
// 2909.022 us; speedup vs baseline: 5.6847x; 5.6847x over previous
//
#include <hip/hip_runtime.h>
#include <math.h>

#define BATCH 4
#define MMDIM 256
#define NNDIM 256
#define CH 64
#define NMODES 32
#define HID 128
#define NLAYERS 4

// ---------------- setup kernels ----------------

// T[k][n] = cos(pi*(n+0.5)*k/256)*sqrt(2/256), row 0 scaled by 1/sqrt(2).
// Only the first 32 rows of the DCT matrix are ever used by the reference
// (truncation to MODES happens before any other use), and M==N so one table.
__global__ __launch_bounds__(256) void k_build_T(float* __restrict__ T) {
    int k = blockIdx.x, n = threadIdx.x;
    double v = cos(M_PI * (n + 0.5) * (double)k / 256.0) * sqrt(2.0 / 256.0);
    if (k == 0) v *= 0.7071067811865476;
    T[k * 256 + n] = (float)v;
}

// fw: [L][64][64][32] (l,i,o,y)  ->  wt: [L][32][64][64] (l,y,i,o)
__global__ __launch_bounds__(256) void k_wt(const float* __restrict__ fw, float* __restrict__ wt) {
    int idx = blockIdx.x * 256 + threadIdx.x;   // over L*32*64*64 = 524288
    int l = idx >> 17, r = idx & 131071;
    int y = r >> 12, i = (r >> 6) & 63, o = r & 63;
    wt[idx] = fw[((l * 64 + i) * 64 + o) * 32 + y];
}

// Fuse the two head matmuls: W_eff[c] = sum_j W_o2[j]*W_o1[j][c]; b_eff = W_o2.b_o1 + b_o2
__global__ void k_head(const float* __restrict__ W_o1, const float* __restrict__ b_o1,
                       const float* __restrict__ W_o2, const float* __restrict__ b_o2,
                       float* __restrict__ Weff, float* __restrict__ beff) {
    int c = threadIdx.x;  // 64
    float acc = 0.f;
    for (int j = 0; j < 128; j++) acc += W_o2[j] * W_o1[j * 64 + c];
    Weff[c] = acc;
    if (c == 0) {
        float bb = 0.f;
        for (int j = 0; j < 128; j++) bb += W_o2[j] * b_o1[j];
        beff[0] = bb + b_o2[0];
    }
}

// x64[p][c] = sum_d xin[p][d]*W_in[c][d] + b_in[c]   (4 pixels per 256-thread block)
__global__ __launch_bounds__(256) void k_inproj(const float* __restrict__ xin,
                                                const float* __restrict__ W_in,
                                                const float* __restrict__ b_in,
                                                float* __restrict__ x64) {
    int t = threadIdx.x;
    long p = (long)blockIdx.x * 4 + (t >> 6);
    int c = t & 63;
    const float* xr = xin + p * 12;
    float acc = b_in[c];
#pragma unroll
    for (int d = 0; d < 12; d++) acc += xr[d] * W_in[c * 12 + d];
    x64[p * 64 + c] = acc;
}

// ---------------- per-layer kernels ----------------

// Forward DCT along one axis, keep 32 modes.
// Block = one (b, f) slab. Stages the 256x64 slab in LDS, each thread computes
// 8 (y,c) outputs. X layout: [b*256+f][32][64] = (b,f,y,c).
__global__ __launch_bounds__(256) void k_dct(const float* __restrict__ x, const float* __restrict__ T,
                                             float* __restrict__ X, long strideA, long strideF) {
    __shared__ float lds[256 * 64];   // 64 KiB
    int t = threadIdx.x;
    int b = blockIdx.x >> 8, f = blockIdx.x & 255;
    const float* base = x + (long)b * (256L * 256 * 64) + (long)f * strideF;
    int c = t & 63, grp = t >> 6;

    if (strideA == 64) {  // contiguous slab: vectorized load
        const float4* src = (const float4*)base;
        float4* dst = (float4*)lds;
        for (int k = t; k < 4096; k += 256) dst[k] = src[k];
    } else {
        for (int a0 = 0; a0 < 256; a0 += 4) {
            int a = a0 + grp;
            lds[a * 64 + c] = base[(long)a * strideA + c];
        }
    }
    __syncthreads();

    float acc[8];
#pragma unroll
    for (int i = 0; i < 8; i++) acc[i] = 0.f;
    int ybase = grp * 8;
#pragma unroll 2
    for (int a = 0; a < 256; a++) {
        float xv = lds[a * 64 + c];
#pragma unroll
        for (int i = 0; i < 8; i++) acc[i] += xv * T[(ybase + i) * 256 + a];
    }
    float* outp = X + ((long)blockIdx.x * 32 + ybase) * 64 + c;
#pragma unroll
    for (int i = 0; i < 8; i++) outp[i * 64] = acc[i];
}

// Channel mix per mode: Xm[bf][y][o] = sum_i X[bf][y][i] * wt[y][i][o]
__global__ __launch_bounds__(256) void k_mix(const float* __restrict__ X,
                                             const float* __restrict__ wt,
                                             float* __restrict__ Xm) {
    __shared__ float lds[32 * 64];
    int t = threadIdx.x;
    const float* base = X + (long)blockIdx.x * 2048;
    for (int k = t; k < 2048; k += 256) lds[k] = base[k];
    __syncthreads();
    int o = t & 63, grp = t >> 6;
    float* outp = Xm + (long)blockIdx.x * 2048;
    for (int yy = 0; yy < 8; yy++) {
        int y = grp * 8 + yy;
        const float* w = wt + (long)y * 4096 + o;
        const float* xr = lds + y * 64;
        float acc = 0.f;
#pragma unroll 16
        for (int i = 0; i < 64; i++) acc += xr[i] * w[i * 64];
        outp[y * 64 + o] = acc;
    }
}

// Inverse transform: h[b, a, f (or f, a), o] (+)= sum_y Xm[bf][y][o]*T[y][a]
__global__ __launch_bounds__(256) void k_idct(const float* __restrict__ Xm, const float* __restrict__ T,
                                              float* __restrict__ h, long strideA, long strideF, int accum) {
    __shared__ float lds[32 * 64];
    int t = threadIdx.x;
    int b = blockIdx.x >> 8, f = blockIdx.x & 255;
    const float* base = Xm + (long)blockIdx.x * 2048;
    for (int k = t; k < 2048; k += 256) lds[k] = base[k];
    __syncthreads();
    int o = t & 63, grp = t >> 6;
    float* outp = h + (long)b * (256L * 256 * 64) + (long)f * strideF;
    for (int aa = 0; aa < 64; aa++) {
        int a = grp * 64 + aa;
        float acc = 0.f;
#pragma unroll
        for (int y = 0; y < 32; y++) acc += lds[y * 64 + o] * T[y * 256 + a];
        long off = (long)a * strideA + o;
        if (accum) outp[off] += acc;
        else outp[off] = acc;
    }
}

// Fused FFN + residual (+ fused head on the last layer).
// Block = 64 pixels, 256 threads. Two phases through LDS; per-thread register
// footprint kept < ~80 VGPRs (the R0 version spilled hr[64]+oacc[64] ->
// 16.7 GB of scratch traffic per dispatch).
#define HS_STRIDE 68   // 64ch + pad, float4-aligned (17 float4)
#define AS_STRIDE 132  // 128hid + pad, float4-aligned (33 float4)
__global__ __launch_bounds__(256) void k_ff(const float* __restrict__ h, float* __restrict__ x,
                                            const float* __restrict__ W1, const float* __restrict__ b1,
                                            const float* __restrict__ W2, const float* __restrict__ b2,
                                            const float* __restrict__ Weff, const float* __restrict__ beff,
                                            float* __restrict__ out, int last) {
    __shared__ float hs[64 * HS_STRIDE];   // 17.4 KB
    __shared__ float as_[64 * AS_STRIDE];  // 33.8 KB
    int t = threadIdx.x;
    long p0 = (long)blockIdx.x * 64;

    // load h tile (64 px x 64 ch), vectorized
    {
        const float4* src = (const float4*)(h + p0 * 64);
        for (int k = t; k < 1024; k += 256) {
            int p = k >> 4, q = k & 15;
            *((float4*)(hs + p * HS_STRIDE + 4 * q)) = src[k];
        }
    }
    __syncthreads();

    // phase 1: A = relu(H @ W1^T + b1). Thread owns j = t&127, half the pixels.
    {
        int j = t & 127, ph = t >> 7;
        float4 w1r[16];
        const float4* w1p = (const float4*)(W1 + j * 64);
#pragma unroll
        for (int q = 0; q < 16; q++) w1r[q] = w1p[q];
        float bj = b1[j];
        for (int pp = 0; pp < 32; pp++) {
            int p = ph * 32 + pp;
            const float4* hrow = (const float4*)(hs + p * HS_STRIDE);
            float acc = bj;
#pragma unroll
            for (int q = 0; q < 16; q++) {
                float4 hv = hrow[q];   // broadcast across wave (free)
                acc += hv.x * w1r[q].x + hv.y * w1r[q].y + hv.z * w1r[q].z + hv.w * w1r[q].w;
            }
            as_[p * AS_STRIDE + j] = fmaxf(acc, 0.f);
        }
    }
    __syncthreads();

    // phase 2: O = A @ W2^T + b2. Thread owns c = t&63, 16 pixels.
    int c = t & 63, pg = t >> 6;
    float acc[16];
#pragma unroll
    for (int i = 0; i < 16; i++) acc[i] = 0.f;
    for (int jc = 0; jc < 128; jc += 32) {
        float4 w2r[8];
        const float4* w2p = (const float4*)(W2 + c * 128 + jc);
#pragma unroll
        for (int q = 0; q < 8; q++) w2r[q] = w2p[q];
#pragma unroll
        for (int i = 0; i < 16; i++) {
            int p = pg * 16 + i;
            const float4* arow = (const float4*)(as_ + p * AS_STRIDE + jc);
            float a = acc[i];
#pragma unroll
            for (int q = 0; q < 8; q++) {
                float4 av = arow[q];   // broadcast across wave (free)
                a += av.x * w2r[q].x + av.y * w2r[q].y + av.z * w2r[q].z + av.w * w2r[q].w;
            }
            acc[i] = a;
        }
    }
    float bc = b2[c];

    if (last) {
        // head: out[p] = beff + sum_c (o[p][c]) * Weff[c]; wave lanes = c 0..63
        float wc = Weff[c];
        float be = beff[0];
#pragma unroll
        for (int i = 0; i < 16; i++) {
            float v = (acc[i] + bc) * wc;
#pragma unroll
            for (int m = 1; m < 64; m <<= 1) v += __shfl_xor(v, m, 64);
            if (c == 0) out[p0 + pg * 16 + i] = v + be;
        }
    } else {
        float* xb = x + (p0 + pg * 16) * 64 + c;
#pragma unroll
        for (int i = 0; i < 16; i++) {
            xb[i * 64] += acc[i] + bc;   // lanes c 0..63 -> coalesced 256B
        }
    }
}

// ---------------- launcher ----------------

extern "C" void kernel_launch(void* const* d_in, const int* in_sizes, int n_in,
                              void* d_out, int out_size, void* d_ws, size_t ws_size,
                              hipStream_t stream) {
    const float* x_in = (const float*)d_in[0];
    const float* W_in = (const float*)d_in[1];
    const float* b_in = (const float*)d_in[2];
    const float* fw0  = (const float*)d_in[3];
    const float* fw1  = (const float*)d_in[4];
    const float* ffW1 = (const float*)d_in[5];
    const float* ffb1 = (const float*)d_in[6];
    const float* ffW2 = (const float*)d_in[7];
    const float* ffb2 = (const float*)d_in[8];
    const float* W_o1 = (const float*)d_in[9];
    const float* b_o1 = (const float*)d_in[10];
    const float* W_o2 = (const float*)d_in[11];
    const float* b_o2 = (const float*)d_in[12];
    float* out = (float*)d_out;

    // workspace layout (floats). Total ~155 MB.
    float* ws   = (float*)d_ws;
    float* T    = ws;                                   // 32*256      = 8192
    float* w0t  = T + 8192;                             // 4*32*64*64  = 524288
    float* w1t  = w0t + (long)NLAYERS * NMODES * CH * CH;
    float* Weff = w1t + (long)NLAYERS * NMODES * CH * CH;  // 64
    float* beff = Weff + 64;                            // 1 (+pad)
    float* x64  = beff + 64;                            // 4*256*256*64 = 16777216
    float* h    = x64 + (long)BATCH * MMDIM * NNDIM * CH;
    float* A    = h + (long)BATCH * MMDIM * NNDIM * CH; // 4*256*32*64 = 2097152
    float* Am   = A + (long)BATCH * MMDIM * NMODES * CH;

    k_build_T<<<32, 256, 0, stream>>>(T);
    k_wt<<<2048, 256, 0, stream>>>(fw0, w0t);
    k_wt<<<2048, 256, 0, stream>>>(fw1, w1t);
    k_head<<<1, 64, 0, stream>>>(W_o1, b_o1, W_o2, b_o2, Weff, beff);
    k_inproj<<<65536, 256, 0, stream>>>(x_in, W_in, b_in, x64);

    for (int l = 0; l < NLAYERS; l++) {
        // y-path: DCT along n (contiguous), mix with w0, inverse, write h
        k_dct<<<1024, 256, 0, stream>>>(x64, T, A, 64L, 16384L);
        k_mix<<<1024, 256, 0, stream>>>(A, w0t + (long)l * NMODES * CH * CH, Am);
        k_idct<<<1024, 256, 0, stream>>>(Am, T, h, 64L, 16384L, 0);
        // x-path: DCT along m (strided), mix with w1, inverse, accumulate into h
        k_dct<<<1024, 256, 0, stream>>>(x64, T, A, 16384L, 64L);
        k_mix<<<1024, 256, 0, stream>>>(A, w1t + (long)l * NMODES * CH * CH, Am);
        k_idct<<<1024, 256, 0, stream>>>(Am, T, h, 16384L, 64L, 1);
        // fused FFN + residual (+ head on last layer)
        k_ff<<<4096, 256, 0, stream>>>(h, x64,
            ffW1 + (long)l * HID * CH, ffb1 + (long)l * HID,
            ffW2 + (long)l * CH * HID, ffb2 + (long)l * CH,
            Weff, beff, out, (l == NLAYERS - 1) ? 1 : 0);
    }
}

// Round 3
// 2073.087 us; speedup vs baseline: 7.9769x; 1.4032x over previous
//
#include <hip/hip_runtime.h>
#include <math.h>

#define BATCH 4
#define MMDIM 256
#define NNDIM 256
#define CH 64
#define NMODES 32
#define HID 128
#define NLAYERS 4

typedef __attribute__((ext_vector_type(8))) short bfrag;   // 8 bf16 (4 VGPRs)
typedef __attribute__((ext_vector_type(4))) float f32x4;

__device__ inline ushort f2bf(float x) {   // RTN-even f32 -> bf16
    union { float f; uint u; } v; v.f = x;
    uint r = v.u + 0x7fff + ((v.u >> 16) & 1);
    return (ushort)(r >> 16);
}
__device__ inline float bf2f(ushort h) {
    union { uint u; float f; } v; v.u = (uint)h << 16; return v.f;
}

// ---------------- setup kernels ----------------

// T[k][n] = cos(pi*(n+0.5)*k/256)*sqrt(2/256), row 0 scaled by 1/sqrt(2).
__global__ __launch_bounds__(256) void k_build_T(float* __restrict__ T) {
    int k = blockIdx.x, n = threadIdx.x;
    double v = cos(M_PI * (n + 0.5) * (double)k / 256.0) * sqrt(2.0 / 256.0);
    if (k == 0) v *= 0.7071067811865476;
    T[k * 256 + n] = (float)v;
}

// fw: [L][64][64][32] (l,i,o,y)  ->  wt: [L][32][64][64] (l,y,i,o)
__global__ __launch_bounds__(256) void k_wt(const float* __restrict__ fw, float* __restrict__ wt) {
    int idx = blockIdx.x * 256 + threadIdx.x;
    int l = idx >> 17, r = idx & 131071;
    int y = r >> 12, i = (r >> 6) & 63, o = r & 63;
    wt[idx] = fw[((l * 64 + i) * 64 + o) * 32 + y];
}

// Fragment-ready bf16 hi/lo for an [N x K] row-major weight (L layers).
// Layout: [l][nt][ks][lane][jj]; b_frag(nt,ks) lane elem jj = W[nt*16+(lane&15)][ks*32+(lane>>4)*8+jj]
__global__ __launch_bounds__(256) void k_wfrag(const float* __restrict__ W,
                                               ushort* __restrict__ hi, ushort* __restrict__ lo,
                                               int N, int K) {
    int idx = blockIdx.x * 256 + threadIdx.x;
    int per_l = N * K;
    int l = idx / per_l, r = idx % per_l;
    int jj = r & 7, lane = (r >> 3) & 63;
    int ks = (r >> 9) % (K >> 5);
    int nt = r / (512 * (K >> 5));
    int row = nt * 16 + (lane & 15);
    int col = ks * 32 + ((lane >> 4) << 3) + jj;
    float v = W[(long)l * per_l + row * K + col];
    ushort h = f2bf(v);
    hi[idx] = h;
    lo[idx] = f2bf(v - bf2f(h));
}

// Fuse head: W_eff[c] = sum_j W_o2[j]*W_o1[j][c]; b_eff = W_o2.b_o1 + b_o2
__global__ void k_head(const float* __restrict__ W_o1, const float* __restrict__ b_o1,
                       const float* __restrict__ W_o2, const float* __restrict__ b_o2,
                       float* __restrict__ Weff, float* __restrict__ beff) {
    int c = threadIdx.x;
    float acc = 0.f;
    for (int j = 0; j < 128; j++) acc += W_o2[j] * W_o1[j * 64 + c];
    Weff[c] = acc;
    if (c == 0) {
        float bb = 0.f;
        for (int j = 0; j < 128; j++) bb += W_o2[j] * b_o1[j];
        beff[0] = bb + b_o2[0];
    }
}

// x64[p][c] = sum_d xin[p][d]*W_in[c][d] + b_in[c]
__global__ __launch_bounds__(256) void k_inproj(const float* __restrict__ xin,
                                                const float* __restrict__ W_in,
                                                const float* __restrict__ b_in,
                                                float* __restrict__ x64) {
    int t = threadIdx.x;
    long p = (long)blockIdx.x * 4 + (t >> 6);
    int c = t & 63;
    const float* xr = xin + p * 12;
    float acc = b_in[c];
#pragma unroll
    for (int d = 0; d < 12; d++) acc += xr[d] * W_in[c * 12 + d];
    x64[p * 64 + c] = acc;
}

// ---------------- per-layer kernels (transforms, f32) ----------------

__global__ __launch_bounds__(256) void k_dct(const float* __restrict__ x, const float* __restrict__ T,
                                             float* __restrict__ X, long strideA, long strideF) {
    __shared__ float lds[256 * 64];
    int t = threadIdx.x;
    int b = blockIdx.x >> 8, f = blockIdx.x & 255;
    const float* base = x + (long)b * (256L * 256 * 64) + (long)f * strideF;
    int c = t & 63, grp = t >> 6;

    if (strideA == 64) {
        const float4* src = (const float4*)base;
        float4* dst = (float4*)lds;
        for (int k = t; k < 4096; k += 256) dst[k] = src[k];
    } else {
        for (int a0 = 0; a0 < 256; a0 += 4) {
            int a = a0 + grp;
            lds[a * 64 + c] = base[(long)a * strideA + c];
        }
    }
    __syncthreads();

    float acc[8];
#pragma unroll
    for (int i = 0; i < 8; i++) acc[i] = 0.f;
    int ybase = grp * 8;
#pragma unroll 2
    for (int a = 0; a < 256; a++) {
        float xv = lds[a * 64 + c];
#pragma unroll
        for (int i = 0; i < 8; i++) acc[i] += xv * T[(ybase + i) * 256 + a];
    }
    float* outp = X + ((long)blockIdx.x * 32 + ybase) * 64 + c;
#pragma unroll
    for (int i = 0; i < 8; i++) outp[i * 64] = acc[i];
}

__global__ __launch_bounds__(256) void k_mix(const float* __restrict__ X,
                                             const float* __restrict__ wt,
                                             float* __restrict__ Xm) {
    __shared__ float lds[32 * 64];
    int t = threadIdx.x;
    const float* base = X + (long)blockIdx.x * 2048;
    for (int k = t; k < 2048; k += 256) lds[k] = base[k];
    __syncthreads();
    int o = t & 63, grp = t >> 6;
    float* outp = Xm + (long)blockIdx.x * 2048;
    for (int yy = 0; yy < 8; yy++) {
        int y = grp * 8 + yy;
        const float* w = wt + (long)y * 4096 + o;
        const float* xr = lds + y * 64;
        float acc = 0.f;
#pragma unroll 16
        for (int i = 0; i < 64; i++) acc += xr[i] * w[i * 64];
        outp[y * 64 + o] = acc;
    }
}

__global__ __launch_bounds__(256) void k_idct(const float* __restrict__ Xm, const float* __restrict__ T,
                                              float* __restrict__ h, long strideA, long strideF, int accum) {
    __shared__ float lds[32 * 64];
    int t = threadIdx.x;
    int b = blockIdx.x >> 8, f = blockIdx.x & 255;
    const float* base = Xm + (long)blockIdx.x * 2048;
    for (int k = t; k < 2048; k += 256) lds[k] = base[k];
    __syncthreads();
    int o = t & 63, grp = t >> 6;
    float* outp = h + (long)b * (256L * 256 * 64) + (long)f * strideF;
    for (int aa = 0; aa < 64; aa++) {
        int a = grp * 64 + aa;
        float acc = 0.f;
#pragma unroll
        for (int y = 0; y < 32; y++) acc += lds[y * 64 + o] * T[y * 256 + a];
        long off = (long)a * strideA + o;
        if (accum) outp[off] += acc;
        else outp[off] = acc;
    }
}

// ---------------- FFN via bf16x3 MFMA ----------------
// Block = 64 pixels, 256 threads (4 waves). Wave w owns pixel rows w*16..w*16+15.
// GEMM1: A[64x128] = relu(H[64x64] @ W1^T + b1)   (K=64: 2 k-steps)
// GEMM2: O[64x64]  = A @ W2^T + b2                (K=128: 4 k-steps)
// bf16x3: D += ahi*bhi + ahi*blo + alo*bhi (f32 accum) -> ~2^-15 rel err.
// MFMA 16x16x32 layouts: a lane l elem j = A[l&15][(l>>4)*8+j] (row-major 8-contig k)
//                        b lane l elem j = B[(l>>4)*8+j][l&15]
//                        d lane l reg r  = D[(l>>4)*4+r][l&15]
#define HS 68    // H LDS row stride (floats)
#define AS 132   // A LDS row stride (floats)
__global__ __launch_bounds__(256) void k_ff(const float* __restrict__ h, float* __restrict__ x,
                                            const ushort* __restrict__ W1hi, const ushort* __restrict__ W1lo,
                                            const float* __restrict__ b1,
                                            const ushort* __restrict__ W2hi, const ushort* __restrict__ W2lo,
                                            const float* __restrict__ b2,
                                            const float* __restrict__ Weff, const float* __restrict__ beff,
                                            float* __restrict__ out, int last) {
    __shared__ float Hs_[64 * HS];
    __shared__ float As_[64 * AS];
    int t = threadIdx.x;
    int lane = t & 63, wv = t >> 6;
    int l15 = lane & 15, l4 = lane >> 4;
    long p0 = (long)blockIdx.x * 64;

    // stage H tile (64px x 64ch), vectorized
    {
        const float4* src = (const float4*)(h + p0 * 64);
        for (int k = t; k < 1024; k += 256) {
            int p = k >> 4, q = k & 15;
            *(float4*)(&Hs_[p * HS + q * 4]) = src[k];
        }
    }
    __syncthreads();

    // ---- GEMM1 ----
    f32x4 acc1[8];
#pragma unroll
    for (int nt = 0; nt < 8; nt++) acc1[nt] = (f32x4){0.f, 0.f, 0.f, 0.f};

#pragma unroll
    for (int ks = 0; ks < 2; ks++) {
        const float* hp = &Hs_[(wv * 16 + l15) * HS + ks * 32 + l4 * 8];
        bfrag ahi, alo;
#pragma unroll
        for (int j = 0; j < 8; j++) {
            float v = hp[j];
            ushort hh = f2bf(v);
            ahi[j] = (short)hh;
            alo[j] = (short)f2bf(v - bf2f(hh));
        }
#pragma unroll
        for (int nt = 0; nt < 8; nt++) {
            long off = (long)((nt * 2 + ks) * 64 + lane) * 8;
            bfrag bhi = *(const bfrag*)(W1hi + off);
            bfrag blo = *(const bfrag*)(W1lo + off);
            acc1[nt] = __builtin_amdgcn_mfma_f32_16x16x32_bf16(ahi, bhi, acc1[nt], 0, 0, 0);
            acc1[nt] = __builtin_amdgcn_mfma_f32_16x16x32_bf16(ahi, blo, acc1[nt], 0, 0, 0);
            acc1[nt] = __builtin_amdgcn_mfma_f32_16x16x32_bf16(alo, bhi, acc1[nt], 0, 0, 0);
        }
    }
    // bias + relu + scatter to As_
#pragma unroll
    for (int nt = 0; nt < 8; nt++) {
        float bj = b1[nt * 16 + l15];
#pragma unroll
        for (int r = 0; r < 4; r++) {
            float v = fmaxf(acc1[nt][r] + bj, 0.f);
            As_[(wv * 16 + l4 * 4 + r) * AS + nt * 16 + l15] = v;
        }
    }
    __syncthreads();

    // ---- GEMM2 ----
    f32x4 acc2[4];
#pragma unroll
    for (int nt = 0; nt < 4; nt++) acc2[nt] = (f32x4){0.f, 0.f, 0.f, 0.f};

#pragma unroll
    for (int ks = 0; ks < 4; ks++) {
        const float* ap = &As_[(wv * 16 + l15) * AS + ks * 32 + l4 * 8];
        bfrag ahi, alo;
#pragma unroll
        for (int j = 0; j < 8; j++) {
            float v = ap[j];
            ushort hh = f2bf(v);
            ahi[j] = (short)hh;
            alo[j] = (short)f2bf(v - bf2f(hh));
        }
#pragma unroll
        for (int nt = 0; nt < 4; nt++) {
            long off = (long)((nt * 4 + ks) * 64 + lane) * 8;
            bfrag bhi = *(const bfrag*)(W2hi + off);
            bfrag blo = *(const bfrag*)(W2lo + off);
            acc2[nt] = __builtin_amdgcn_mfma_f32_16x16x32_bf16(ahi, bhi, acc2[nt], 0, 0, 0);
            acc2[nt] = __builtin_amdgcn_mfma_f32_16x16x32_bf16(ahi, blo, acc2[nt], 0, 0, 0);
            acc2[nt] = __builtin_amdgcn_mfma_f32_16x16x32_bf16(alo, bhi, acc2[nt], 0, 0, 0);
        }
    }

    // ---- epilogue ----
    if (last) {
        float be = beff[0];
#pragma unroll
        for (int r = 0; r < 4; r++) {
            float v = 0.f;
#pragma unroll
            for (int nt = 0; nt < 4; nt++) {
                int c = nt * 16 + l15;
                v += (acc2[nt][r] + b2[c]) * Weff[c];
            }
            v += __shfl_xor(v, 1, 64);
            v += __shfl_xor(v, 2, 64);
            v += __shfl_xor(v, 4, 64);
            v += __shfl_xor(v, 8, 64);
            if (l15 == 0) out[p0 + wv * 16 + l4 * 4 + r] = v + be;
        }
    } else {
#pragma unroll
        for (int nt = 0; nt < 4; nt++) {
            int c = nt * 16 + l15;
            float bc = b2[c];
#pragma unroll
            for (int r = 0; r < 4; r++) {
                long off = (p0 + wv * 16 + l4 * 4 + r) * 64 + c;
                x[off] += acc2[nt][r] + bc;
            }
        }
    }
}

// ---------------- launcher ----------------

extern "C" void kernel_launch(void* const* d_in, const int* in_sizes, int n_in,
                              void* d_out, int out_size, void* d_ws, size_t ws_size,
                              hipStream_t stream) {
    const float* x_in = (const float*)d_in[0];
    const float* W_in = (const float*)d_in[1];
    const float* b_in = (const float*)d_in[2];
    const float* fw0  = (const float*)d_in[3];
    const float* fw1  = (const float*)d_in[4];
    const float* ffW1 = (const float*)d_in[5];
    const float* ffb1 = (const float*)d_in[6];
    const float* ffW2 = (const float*)d_in[7];
    const float* ffb2 = (const float*)d_in[8];
    const float* W_o1 = (const float*)d_in[9];
    const float* b_o1 = (const float*)d_in[10];
    const float* W_o2 = (const float*)d_in[11];
    const float* b_o2 = (const float*)d_in[12];
    float* out = (float*)d_out;

    // workspace layout (floats)
    float* ws   = (float*)d_ws;
    float* T    = ws;                                   // 8192
    float* w0t  = T + 8192;                             // 524288
    float* w1t  = w0t + (long)NLAYERS * NMODES * CH * CH;
    float* Weff = w1t + (long)NLAYERS * NMODES * CH * CH;  // 64
    float* beff = Weff + 64;
    float* x64  = beff + 64;                            // 16777216
    float* h    = x64 + (long)BATCH * MMDIM * NNDIM * CH;
    float* A    = h + (long)BATCH * MMDIM * NNDIM * CH; // 2097152
    float* Am   = A + (long)BATCH * MMDIM * NMODES * CH;
    // bf16 fragment-ready FF weights (after Am): L*8192 ushorts each
    ushort* W1f_hi = (ushort*)(Am + (long)BATCH * MMDIM * NMODES * CH);
    ushort* W1f_lo = W1f_hi + (long)NLAYERS * HID * CH;
    ushort* W2f_hi = W1f_lo + (long)NLAYERS * HID * CH;
    ushort* W2f_lo = W2f_hi + (long)NLAYERS * CH * HID;

    k_build_T<<<32, 256, 0, stream>>>(T);
    k_wt<<<2048, 256, 0, stream>>>(fw0, w0t);
    k_wt<<<2048, 256, 0, stream>>>(fw1, w1t);
    k_wfrag<<<(NLAYERS * HID * CH) / 256, 256, 0, stream>>>(ffW1, W1f_hi, W1f_lo, HID, CH);
    k_wfrag<<<(NLAYERS * CH * HID) / 256, 256, 0, stream>>>(ffW2, W2f_hi, W2f_lo, CH, HID);
    k_head<<<1, 64, 0, stream>>>(W_o1, b_o1, W_o2, b_o2, Weff, beff);
    k_inproj<<<65536, 256, 0, stream>>>(x_in, W_in, b_in, x64);

    for (int l = 0; l < NLAYERS; l++) {
        k_dct<<<1024, 256, 0, stream>>>(x64, T, A, 64L, 16384L);
        k_mix<<<1024, 256, 0, stream>>>(A, w0t + (long)l * NMODES * CH * CH, Am);
        k_idct<<<1024, 256, 0, stream>>>(Am, T, h, 64L, 16384L, 0);
        k_dct<<<1024, 256, 0, stream>>>(x64, T, A, 16384L, 64L);
        k_mix<<<1024, 256, 0, stream>>>(A, w1t + (long)l * NMODES * CH * CH, Am);
        k_idct<<<1024, 256, 0, stream>>>(Am, T, h, 16384L, 64L, 1);
        k_ff<<<4096, 256, 0, stream>>>(h, x64,
            W1f_hi + (long)l * HID * CH, W1f_lo + (long)l * HID * CH,
            ffb1 + (long)l * HID,
            W2f_hi + (long)l * CH * HID, W2f_lo + (long)l * CH * HID,
            ffb2 + (long)l * CH,
            Weff, beff, out, (l == NLAYERS - 1) ? 1 : 0);
    }
}

// Round 5
// 768.355 us; speedup vs baseline: 21.5223x; 2.6981x over previous
//
#include <hip/hip_runtime.h>
#include <math.h>

#define BATCH 4
#define MMDIM 256
#define NNDIM 256
#define CH 64
#define NMODES 32
#define HID 128
#define NLAYERS 4
#define XPLANE 16777216L   // ushorts per hi/lo plane of an xbf tensor

typedef __attribute__((ext_vector_type(8))) short bfrag;    // 8 bf16
typedef __attribute__((ext_vector_type(8))) ushort u16x8;   // 16B
typedef __attribute__((ext_vector_type(4))) float f32x4;

__device__ inline ushort f2bf(float x) {   // RTN-even f32 -> bf16
    union { float f; uint u; } v; v.f = x;
    uint r = v.u + 0x7fff + ((v.u >> 16) & 1);
    return (ushort)(r >> 16);
}
__device__ inline float bf2f(ushort h) {
    union { uint u; float f; } v; v.u = (uint)h << 16; return v.f;
}
#define MFMA __builtin_amdgcn_mfma_f32_16x16x32_bf16

// ---------------- setup kernels ----------------

__global__ __launch_bounds__(256) void k_build_T(float* __restrict__ T) {
    int k = blockIdx.x, n = threadIdx.x;
    double v = cos(M_PI * (n + 0.5) * (double)k / 256.0) * sqrt(2.0 / 256.0);
    if (k == 0) v *= 0.7071067811865476;
    T[k * 256 + n] = (float)v;
}

// fw: [L][64][64][32] (l,i,o,y) -> wt: [L][32][64][64] (l,y,i,o)  (mix weights, f32)
__global__ __launch_bounds__(256) void k_wt(const float* __restrict__ fw, float* __restrict__ wt) {
    int idx = blockIdx.x * 256 + threadIdx.x;
    int l = idx >> 17, r = idx & 131071;
    int y = r >> 12, i = (r >> 6) & 63, o = r & 63;
    wt[idx] = fw[((l * 64 + i) * 64 + o) * 32 + y];
}

// DCT A-frags: Tf[yt(2)][ks(8)][lane(64)][j(8)] = T[yt*16+(lane&15)][ks*32+(lane>>4)*8+j], hi then +8192 lo
__global__ __launch_bounds__(256) void k_Tfrag(const float* __restrict__ T, ushort* __restrict__ Tf) {
    int idx = blockIdx.x * 256 + threadIdx.x;   // 8192
    int j = idx & 7, lane = (idx >> 3) & 63, ks = (idx >> 9) & 7, yt = idx >> 12;
    float v = T[(yt * 16 + (lane & 15)) * 256 + ks * 32 + ((lane >> 4) << 3) + j];
    ushort hh = f2bf(v);
    Tf[idx] = hh; Tf[idx + 8192] = f2bf(v - bf2f(hh));
}

// iDCT A-frags: Ttf[at(16)][lane(64)][j(8)] = T[(lane>>4)*8+j][at*16+(lane&15)], hi then +8192 lo
__global__ __launch_bounds__(256) void k_Ttfrag(const float* __restrict__ T, ushort* __restrict__ Ttf) {
    int idx = blockIdx.x * 256 + threadIdx.x;   // 8192
    int j = idx & 7, lane = (idx >> 3) & 63, at = idx >> 9;
    float v = T[(((lane >> 4) << 3) + j) * 256 + at * 16 + (lane & 15)];
    ushort hh = f2bf(v);
    Ttf[idx] = hh; Ttf[idx + 8192] = f2bf(v - bf2f(hh));
}

// FF weight frags (validated R3): [l][nt][ks][lane][jj]
__global__ __launch_bounds__(256) void k_wfrag(const float* __restrict__ W,
                                               ushort* __restrict__ hi, ushort* __restrict__ lo,
                                               int N, int K) {
    int idx = blockIdx.x * 256 + threadIdx.x;
    int per_l = N * K;
    int l = idx / per_l, r = idx % per_l;
    int jj = r & 7, lane = (r >> 3) & 63;
    int ks = (r >> 9) % (K >> 5);
    int nt = r / (512 * (K >> 5));
    int row = nt * 16 + (lane & 15);
    int col = ks * 32 + ((lane >> 4) << 3) + jj;
    float v = W[(long)l * per_l + row * K + col];
    ushort h = f2bf(v);
    hi[idx] = h;
    lo[idx] = f2bf(v - bf2f(h));
}

__global__ void k_head(const float* __restrict__ W_o1, const float* __restrict__ b_o1,
                       const float* __restrict__ W_o2, const float* __restrict__ b_o2,
                       float* __restrict__ Weff, float* __restrict__ beff) {
    int c = threadIdx.x;
    float acc = 0.f;
    for (int j = 0; j < 128; j++) acc += W_o2[j] * W_o1[j * 64 + c];
    Weff[c] = acc;
    if (c == 0) {
        float bb = 0.f;
        for (int j = 0; j < 128; j++) bb += W_o2[j] * b_o1[j];
        beff[0] = bb + b_o2[0];
    }
}

// Fused input projection -> bf16 hi/lo in [b][m][c][n] layout.
// grid 4096 = b*1024 + m*4 + ntile; block 256 = c(64) x ngroup(4).
__global__ __launch_bounds__(256) void k_inproj_bf(const float* __restrict__ xin,
                                                   const float* __restrict__ W_in,
                                                   const float* __restrict__ b_in,
                                                   ushort* __restrict__ xbf) {
    __shared__ __align__(16) ushort tile[2][64][72];
    int t = threadIdx.x;
    int bid = blockIdx.x;
    int b = bid >> 10, m = (bid >> 2) & 255, n0 = (bid & 3) * 64;
    int c = t & 63, ng = t >> 6;
    long pbase = (long)(b * 256 + m) * 256 + n0;
    float w[12];
#pragma unroll
    for (int d = 0; d < 12; d++) w[d] = W_in[c * 12 + d];
    float bc = b_in[c];
#pragma unroll 4
    for (int i = 0; i < 16; i++) {
        int nl = ng * 16 + i;
        const float* xr = xin + (pbase + nl) * 12;   // wave-uniform address
        float acc = bc;
#pragma unroll
        for (int d = 0; d < 12; d++) acc += xr[d] * w[d];
        ushort hh = f2bf(acc);
        tile[0][c][nl] = hh;
        tile[1][c][nl] = f2bf(acc - bf2f(hh));
    }
    __syncthreads();
    int c2 = t >> 2, ch = t & 3;
#pragma unroll
    for (int pl = 0; pl < 2; pl++) {
        const ushort* s = &tile[pl][c2][ch * 16];
        u16x8 v0 = *(const u16x8*)s;
        u16x8 v1 = *(const u16x8*)(s + 8);
        ushort* dst = xbf + (long)pl * XPLANE + ((long)(b * 256 + m) * 64 + c2) * 256 + n0 + ch * 16;
        *(u16x8*)dst = v0; *(u16x8*)(dst + 8) = v1;
    }
}

// bf16 transpose: xbf_y [b][m][c][n] -> xbf_x [b][n][c][m].
// grid 8192 = pl(2) x b(4) x c(64) x mt(4) x nt(4)
__global__ __launch_bounds__(256) void k_tx(const ushort* __restrict__ src, ushort* __restrict__ dst) {
    __shared__ __align__(16) ushort tl[64][72];
    int t = threadIdx.x;
    int bid = blockIdx.x;
    int ntile = bid & 3, mt = (bid >> 2) & 3, c = (bid >> 4) & 63, b = (bid >> 10) & 3, pl = bid >> 12;
    int m0 = mt * 64, n0 = ntile * 64;
    const ushort* sp = src + (long)pl * XPLANE;
    ushort* dp = dst + (long)pl * XPLANE;
    {
        int row = t >> 2, ch = (t & 3) * 16;   // m-local, n-chunk
        const ushort* p = sp + ((long)(b * 256 + m0 + row) * 64 + c) * 256 + n0 + ch;
        u16x8 v0 = *(const u16x8*)p;
        u16x8 v1 = *(const u16x8*)(p + 8);
#pragma unroll
        for (int k = 0; k < 8; k++) tl[ch + k][row] = v0[k];
#pragma unroll
        for (int k = 0; k < 8; k++) tl[ch + 8 + k][row] = v1[k];
    }
    __syncthreads();
    {
        int nrow = t >> 2, mch = (t & 3) * 16;
        const ushort* s = &tl[nrow][mch];
        u16x8 v0 = *(const u16x8*)s;
        u16x8 v1 = *(const u16x8*)(s + 8);
        ushort* p = dp + ((long)(b * 256 + n0 + nrow) * 64 + c) * 256 + m0 + mch;
        *(u16x8*)p = v0; *(u16x8*)(p + 8) = v1;
    }
}

// ---------------- fused spectral kernel: DCT -> mix -> iDCT ----------------
// grid 1024 = b*256 + f.  xbf slab: [f-batch][c(64)][k(256)] bf16 hi/lo, k = contracted axis.
__global__ __launch_bounds__(256) void k_spec(const ushort* __restrict__ xbf,
                                              const ushort* __restrict__ Tf,
                                              const ushort* __restrict__ Ttf,
                                              const float* __restrict__ wt,
                                              float* __restrict__ hdst,
                                              long strideA, long strideF, int accum) {
    __shared__ float Xs[32][68];
    __shared__ __align__(16) ushort Xmb[2][64][40];
    int t = threadIdx.x;
    int lane = t & 63, wv = t >> 6, l15 = lane & 15, l4 = lane >> 4;
    int bf = blockIdx.x;
    const ushort* xb = xbf + (long)bf * 16384;

    // ---- DCT ----
    f32x4 a0 = {0.f, 0.f, 0.f, 0.f}, a1 = {0.f, 0.f, 0.f, 0.f};
    int c0 = wv * 16;
#pragma unroll
    for (int ks = 0; ks < 8; ks++) {
        const ushort* bp = xb + (c0 + l15) * 256 + ks * 32 + l4 * 8;
        bfrag bhi = *(const bfrag*)bp;
        bfrag blo = *(const bfrag*)(bp + XPLANE);
        const ushort* ap0 = Tf + (long)((0 * 8 + ks) * 64 + lane) * 8;
        const ushort* ap1 = Tf + (long)((1 * 8 + ks) * 64 + lane) * 8;
        bfrag a0h = *(const bfrag*)ap0, a0l = *(const bfrag*)(ap0 + 8192);
        bfrag a1h = *(const bfrag*)ap1, a1l = *(const bfrag*)(ap1 + 8192);
        a0 = MFMA(a0h, bhi, a0, 0, 0, 0);
        a0 = MFMA(a0h, blo, a0, 0, 0, 0);
        a0 = MFMA(a0l, bhi, a0, 0, 0, 0);
        a1 = MFMA(a1h, bhi, a1, 0, 0, 0);
        a1 = MFMA(a1h, blo, a1, 0, 0, 0);
        a1 = MFMA(a1l, bhi, a1, 0, 0, 0);
    }
#pragma unroll
    for (int r = 0; r < 4; r++) {
        Xs[l4 * 4 + r][c0 + l15] = a0[r];
        Xs[16 + l4 * 4 + r][c0 + l15] = a1[r];
    }
    __syncthreads();

    // ---- mix ----
    {
        int o = t & 63, yg = t >> 6;
#pragma unroll
        for (int yy = 0; yy < 8; yy++) {
            int y = yg * 8 + yy;
            const float* w = wt + (long)y * 4096 + o;
            const float* xr = Xs[y];
            float a = 0.f;
#pragma unroll 16
            for (int i = 0; i < 64; i++) a += xr[i] * w[i * 64];
            ushort hh = f2bf(a);
            Xmb[0][o][y] = hh;
            Xmb[1][o][y] = f2bf(a - bf2f(hh));
        }
    }
    __syncthreads();

    // ---- iDCT ----
    bfrag vbh[4], vbl[4];
#pragma unroll
    for (int ot = 0; ot < 4; ot++) {
        vbh[ot] = *(const bfrag*)(&Xmb[0][ot * 16 + l15][l4 * 8]);
        vbl[ot] = *(const bfrag*)(&Xmb[1][ot * 16 + l15][l4 * 8]);
    }
    int b = bf >> 8, f = bf & 255;
    float* hb = hdst + (long)b * 4194304 + (long)f * strideF;
#pragma unroll
    for (int ai = 0; ai < 4; ai++) {
        int at = wv * 4 + ai;
        const ushort* ap = Ttf + (long)(at * 64 + lane) * 8;
        bfrag th = *(const bfrag*)ap, tl_ = *(const bfrag*)(ap + 8192);
#pragma unroll
        for (int ot = 0; ot < 4; ot++) {
            f32x4 acc = {0.f, 0.f, 0.f, 0.f};
            acc = MFMA(th, vbh[ot], acc, 0, 0, 0);
            acc = MFMA(th, vbl[ot], acc, 0, 0, 0);
            acc = MFMA(tl_, vbh[ot], acc, 0, 0, 0);
            int arow = at * 16 + l4 * 4;
            float* op = hb + (long)arow * strideA + ot * 16 + l15;
            if (accum) {
#pragma unroll
                for (int r = 0; r < 4; r++) op[(long)r * strideA] += acc[r];
            } else {
#pragma unroll
                for (int r = 0; r < 4; r++) op[(long)r * strideA] = acc[r];
            }
        }
    }
}

// ---------------- FFN via bf16x3 MFMA; residual kept in bf16 hi/lo (xbf_y) ----------------
#define HS 68
#define AS 132
__global__ __launch_bounds__(256) void k_ff(const float* __restrict__ h,
                                            ushort* __restrict__ xbfw,
                                            const ushort* __restrict__ W1hi, const ushort* __restrict__ W1lo,
                                            const float* __restrict__ b1,
                                            const ushort* __restrict__ W2hi, const ushort* __restrict__ W2lo,
                                            const float* __restrict__ b2,
                                            const float* __restrict__ Weff, const float* __restrict__ beff,
                                            float* __restrict__ out, int last) {
    __shared__ __align__(16) float Hs_[64 * HS];
    __shared__ __align__(16) float As_[64 * AS];
    int t = threadIdx.x;
    int lane = t & 63, wv = t >> 6;
    int l15 = lane & 15, l4 = lane >> 4;
    long p0 = (long)blockIdx.x * 64;

    {
        const float4* src = (const float4*)(h + p0 * 64);
        for (int k = t; k < 1024; k += 256) {
            int p = k >> 4, q = k & 15;
            *(float4*)(&Hs_[p * HS + q * 4]) = src[k];
        }
    }
    __syncthreads();

    // GEMM1: A = relu(H @ W1^T + b1)
    f32x4 acc1[8];
#pragma unroll
    for (int nt = 0; nt < 8; nt++) acc1[nt] = (f32x4){0.f, 0.f, 0.f, 0.f};
#pragma unroll
    for (int ks = 0; ks < 2; ks++) {
        const float* hp = &Hs_[(wv * 16 + l15) * HS + ks * 32 + l4 * 8];
        bfrag ahi, alo;
#pragma unroll
        for (int j = 0; j < 8; j++) {
            float v = hp[j];
            ushort hh = f2bf(v);
            ahi[j] = (short)hh;
            alo[j] = (short)f2bf(v - bf2f(hh));
        }
#pragma unroll
        for (int nt = 0; nt < 8; nt++) {
            long off = (long)((nt * 2 + ks) * 64 + lane) * 8;
            bfrag bhi = *(const bfrag*)(W1hi + off);
            bfrag blo = *(const bfrag*)(W1lo + off);
            acc1[nt] = MFMA(ahi, bhi, acc1[nt], 0, 0, 0);
            acc1[nt] = MFMA(ahi, blo, acc1[nt], 0, 0, 0);
            acc1[nt] = MFMA(alo, bhi, acc1[nt], 0, 0, 0);
        }
    }
#pragma unroll
    for (int nt = 0; nt < 8; nt++) {
        float bj = b1[nt * 16 + l15];
#pragma unroll
        for (int r = 0; r < 4; r++) {
            float v = fmaxf(acc1[nt][r] + bj, 0.f);
            As_[(wv * 16 + l4 * 4 + r) * AS + nt * 16 + l15] = v;
        }
    }
    __syncthreads();

    // GEMM2: O = A @ W2^T (+ b2 in epilogue)
    f32x4 acc2[4];
#pragma unroll
    for (int nt = 0; nt < 4; nt++) acc2[nt] = (f32x4){0.f, 0.f, 0.f, 0.f};
#pragma unroll
    for (int ks = 0; ks < 4; ks++) {
        const float* ap = &As_[(wv * 16 + l15) * AS + ks * 32 + l4 * 8];
        bfrag ahi, alo;
#pragma unroll
        for (int j = 0; j < 8; j++) {
            float v = ap[j];
            ushort hh = f2bf(v);
            ahi[j] = (short)hh;
            alo[j] = (short)f2bf(v - bf2f(hh));
        }
#pragma unroll
        for (int nt = 0; nt < 4; nt++) {
            long off = (long)((nt * 4 + ks) * 64 + lane) * 8;
            bfrag bhi = *(const bfrag*)(W2hi + off);
            bfrag blo = *(const bfrag*)(W2lo + off);
            acc2[nt] = MFMA(ahi, bhi, acc2[nt], 0, 0, 0);
            acc2[nt] = MFMA(ahi, blo, acc2[nt], 0, 0, 0);
            acc2[nt] = MFMA(alo, bhi, acc2[nt], 0, 0, 0);
        }
    }

    if (last) {
        float be = beff[0];
#pragma unroll
        for (int r = 0; r < 4; r++) {
            float v = 0.f;
#pragma unroll
            for (int nt = 0; nt < 4; nt++) {
                int c = nt * 16 + l15;
                v += (acc2[nt][r] + b2[c]) * Weff[c];
            }
            v += __shfl_xor(v, 1, 64);
            v += __shfl_xor(v, 2, 64);
            v += __shfl_xor(v, 4, 64);
            v += __shfl_xor(v, 8, 64);
            if (l15 == 0) out[p0 + wv * 16 + l4 * 4 + r] = v + be;
        }
    } else {
        __syncthreads();   // all waves done reading As_
        ushort* tile = (ushort*)As_;   // [2][64][72] ushorts = 18.4 KB <= 33.8 KB
        int b = (int)(p0 >> 16), m = (int)((p0 >> 8) & 255), n0 = (int)(p0 & 255);
        const ushort* rb = xbfw + ((long)(b * 256 + m) * 64) * 256 + n0;
#pragma unroll
        for (int nt = 0; nt < 4; nt++) {
            int c = nt * 16 + l15;
            float bc = b2[c];
            const ushort* rp = rb + (long)c * 256;
#pragma unroll
            for (int r = 0; r < 4; r++) {
                int nl = wv * 16 + l4 * 4 + r;
                float res = bf2f(rp[nl]) + bf2f(rp[nl + XPLANE]);   // f32 residual from hi+lo
                float v = res + acc2[nt][r] + bc;
                ushort hh = f2bf(v);
                tile[(0 * 64 + c) * 72 + nl] = hh;
                tile[(1 * 64 + c) * 72 + nl] = f2bf(v - bf2f(hh));
            }
        }
        __syncthreads();
        int c2 = t >> 2, ch = t & 3;
#pragma unroll
        for (int pl = 0; pl < 2; pl++) {
            const ushort* s = tile + (pl * 64 + c2) * 72 + ch * 16;
            u16x8 v0 = *(const u16x8*)s;
            u16x8 v1 = *(const u16x8*)(s + 8);
            ushort* dst = xbfw + (long)pl * XPLANE + ((long)(b * 256 + m) * 64 + c2) * 256 + n0 + ch * 16;
            *(u16x8*)dst = v0; *(u16x8*)(dst + 8) = v1;
        }
    }
}

// ---------------- launcher ----------------

extern "C" void kernel_launch(void* const* d_in, const int* in_sizes, int n_in,
                              void* d_out, int out_size, void* d_ws, size_t ws_size,
                              hipStream_t stream) {
    const float* x_in = (const float*)d_in[0];
    const float* W_in = (const float*)d_in[1];
    const float* b_in = (const float*)d_in[2];
    const float* fw0  = (const float*)d_in[3];
    const float* fw1  = (const float*)d_in[4];
    const float* ffW1 = (const float*)d_in[5];
    const float* ffb1 = (const float*)d_in[6];
    const float* ffW2 = (const float*)d_in[7];
    const float* ffb2 = (const float*)d_in[8];
    const float* W_o1 = (const float*)d_in[9];
    const float* b_o1 = (const float*)d_in[10];
    const float* W_o2 = (const float*)d_in[11];
    const float* b_o2 = (const float*)d_in[12];
    float* out = (float*)d_out;

    // workspace layout: ~196 MiB total (was ~260 MiB in R4 -> suspected d_ws overflow)
    float* ws   = (float*)d_ws;
    float* T    = ws;                     // 8192
    float* w0t  = T + 8192;               // 524288
    float* w1t  = w0t + 524288;           // 524288
    float* Weff = w1t + 524288;           // 64
    float* beff = Weff + 64;              // 64
    float* h    = beff + 64;              // 16777216 (64 MB)
    ushort* Tfrag  = (ushort*)(h + 16777216);   // 16384
    ushort* Ttfrag = Tfrag + 16384;             // 16384
    ushort* W1f_hi = Ttfrag + 16384;            // 32768
    ushort* W1f_lo = W1f_hi + 32768;
    ushort* W2f_hi = W1f_lo + 32768;
    ushort* W2f_lo = W2f_hi + 32768;
    ushort* xbf_y  = W2f_lo + 32768;            // 2*16777216 (64 MB)
    ushort* xbf_x  = xbf_y + 2 * XPLANE;        // 2*16777216 (64 MB)

    k_build_T<<<32, 256, 0, stream>>>(T);
    k_wt<<<2048, 256, 0, stream>>>(fw0, w0t);
    k_wt<<<2048, 256, 0, stream>>>(fw1, w1t);
    k_Tfrag<<<32, 256, 0, stream>>>(T, Tfrag);
    k_Ttfrag<<<32, 256, 0, stream>>>(T, Ttfrag);
    k_wfrag<<<(NLAYERS * HID * CH) / 256, 256, 0, stream>>>(ffW1, W1f_hi, W1f_lo, HID, CH);
    k_wfrag<<<(NLAYERS * CH * HID) / 256, 256, 0, stream>>>(ffW2, W2f_hi, W2f_lo, CH, HID);
    k_head<<<1, 64, 0, stream>>>(W_o1, b_o1, W_o2, b_o2, Weff, beff);
    k_inproj_bf<<<4096, 256, 0, stream>>>(x_in, W_in, b_in, xbf_y);

    for (int l = 0; l < NLAYERS; l++) {
        // y-path: contract n; h[b][m][a=n][c]: strideA=64, strideF(m)=16384; write
        k_spec<<<1024, 256, 0, stream>>>(xbf_y, Tfrag, Ttfrag, w0t + (long)l * 131072,
                                         h, 64L, 16384L, 0);
        // x-path input: xbf_x[b][n][c][m]
        k_tx<<<8192, 256, 0, stream>>>(xbf_y, xbf_x);
        // x-path: contract m; h[b][a=m][f=n][c]: strideA=16384, strideF(n)=64; accumulate
        k_spec<<<1024, 256, 0, stream>>>(xbf_x, Tfrag, Ttfrag, w1t + (long)l * 131072,
                                         h, 16384L, 64L, 1);
        // FFN + residual (RMW on xbf_y) (+ head on last layer)
        k_ff<<<4096, 256, 0, stream>>>(h, xbf_y,
            W1f_hi + (long)l * HID * CH, W1f_lo + (long)l * HID * CH,
            ffb1 + (long)l * HID,
            W2f_hi + (long)l * CH * HID, W2f_lo + (long)l * CH * HID,
            ffb2 + (long)l * CH,
            Weff, beff, out, (l == NLAYERS - 1) ? 1 : 0);
    }
}

// Round 6
// 725.860 us; speedup vs baseline: 22.7823x; 1.0585x over previous
//
#include <hip/hip_runtime.h>
#include <hip/hip_bf16.h>
#include <math.h>

#define BATCH 4
#define MMDIM 256
#define NNDIM 256
#define CH 64
#define NMODES 32
#define HID 128
#define NLAYERS 4
#define XPLANE 16777216L   // ushorts per hi/lo plane of an xbf tensor

typedef __attribute__((ext_vector_type(8))) short bfrag;    // 8 bf16
typedef __attribute__((ext_vector_type(8))) ushort u16x8;   // 16B
typedef __attribute__((ext_vector_type(4))) float f32x4;

__device__ inline ushort f2bf(float x) {   // RTN-even f32 -> bf16 (setup kernels)
    union { float f; uint u; } v; v.f = x;
    uint r = v.u + 0x7fff + ((v.u >> 16) & 1);
    return (ushort)(r >> 16);
}
__device__ inline float bf2f(ushort h) {
    union { uint u; float f; } v; v.u = (uint)h << 16; return v.f;
}
// fast hi/lo split via HW bf16 cast (hot kernels)
__device__ inline void split(float v, ushort& hi, ushort& lo) {
    __hip_bfloat16 h = __float2bfloat16(v);
    hi = __builtin_bit_cast(ushort, h);
    lo = __builtin_bit_cast(ushort, __float2bfloat16(v - __bfloat162float(h)));
}
#define MFMA __builtin_amdgcn_mfma_f32_16x16x32_bf16

// ---------------- setup kernels ----------------

__global__ __launch_bounds__(256) void k_build_T(float* __restrict__ T) {
    int k = blockIdx.x, n = threadIdx.x;
    double v = cos(M_PI * (n + 0.5) * (double)k / 256.0) * sqrt(2.0 / 256.0);
    if (k == 0) v *= 0.7071067811865476;
    T[k * 256 + n] = (float)v;
}

// fw: [L][64][64][32] (l,i,o,y) -> wt: [L][32][64][64] (l,y,i,o)  (mix weights, f32)
__global__ __launch_bounds__(256) void k_wt(const float* __restrict__ fw, float* __restrict__ wt) {
    int idx = blockIdx.x * 256 + threadIdx.x;
    int l = idx >> 17, r = idx & 131071;
    int y = r >> 12, i = (r >> 6) & 63, o = r & 63;
    wt[idx] = fw[((l * 64 + i) * 64 + o) * 32 + y];
}

// DCT A-frags: Tf[yt(2)][ks(8)][lane(64)][j(8)] = T[yt*16+(lane&15)][ks*32+(lane>>4)*8+j], hi then +8192 lo
__global__ __launch_bounds__(256) void k_Tfrag(const float* __restrict__ T, ushort* __restrict__ Tf) {
    int idx = blockIdx.x * 256 + threadIdx.x;   // 8192
    int j = idx & 7, lane = (idx >> 3) & 63, ks = (idx >> 9) & 7, yt = idx >> 12;
    float v = T[(yt * 16 + (lane & 15)) * 256 + ks * 32 + ((lane >> 4) << 3) + j];
    ushort hh = f2bf(v);
    Tf[idx] = hh; Tf[idx + 8192] = f2bf(v - bf2f(hh));
}

// iDCT A-frags: Ttf[at(16)][lane(64)][j(8)] = T[(lane>>4)*8+j][at*16+(lane&15)], hi then +8192 lo
__global__ __launch_bounds__(256) void k_Ttfrag(const float* __restrict__ T, ushort* __restrict__ Ttf) {
    int idx = blockIdx.x * 256 + threadIdx.x;   // 8192
    int j = idx & 7, lane = (idx >> 3) & 63, at = idx >> 9;
    float v = T[(((lane >> 4) << 3) + j) * 256 + at * 16 + (lane & 15)];
    ushort hh = f2bf(v);
    Ttf[idx] = hh; Ttf[idx + 8192] = f2bf(v - bf2f(hh));
}

// FF weight frags (validated R3): [l][nt][ks][lane][jj]
__global__ __launch_bounds__(256) void k_wfrag(const float* __restrict__ W,
                                               ushort* __restrict__ hi, ushort* __restrict__ lo,
                                               int N, int K) {
    int idx = blockIdx.x * 256 + threadIdx.x;
    int per_l = N * K;
    int l = idx / per_l, r = idx % per_l;
    int jj = r & 7, lane = (r >> 3) & 63;
    int ks = (r >> 9) % (K >> 5);
    int nt = r / (512 * (K >> 5));
    int row = nt * 16 + (lane & 15);
    int col = ks * 32 + ((lane >> 4) << 3) + jj;
    float v = W[(long)l * per_l + row * K + col];
    ushort h = f2bf(v);
    hi[idx] = h;
    lo[idx] = f2bf(v - bf2f(h));
}

__global__ void k_head(const float* __restrict__ W_o1, const float* __restrict__ b_o1,
                       const float* __restrict__ W_o2, const float* __restrict__ b_o2,
                       float* __restrict__ Weff, float* __restrict__ beff) {
    int c = threadIdx.x;
    float acc = 0.f;
    for (int j = 0; j < 128; j++) acc += W_o2[j] * W_o1[j * 64 + c];
    Weff[c] = acc;
    if (c == 0) {
        float bb = 0.f;
        for (int j = 0; j < 128; j++) bb += W_o2[j] * b_o1[j];
        beff[0] = bb + b_o2[0];
    }
}

// Fused input projection -> bf16 hi/lo in [b][m][c][n] layout.
__global__ __launch_bounds__(256) void k_inproj_bf(const float* __restrict__ xin,
                                                   const float* __restrict__ W_in,
                                                   const float* __restrict__ b_in,
                                                   ushort* __restrict__ xbf) {
    __shared__ __align__(16) ushort tile[2][64][72];
    int t = threadIdx.x;
    int bid = blockIdx.x;
    int b = bid >> 10, m = (bid >> 2) & 255, n0 = (bid & 3) * 64;
    int c = t & 63, ng = t >> 6;
    long pbase = (long)(b * 256 + m) * 256 + n0;
    float w[12];
#pragma unroll
    for (int d = 0; d < 12; d++) w[d] = W_in[c * 12 + d];
    float bc = b_in[c];
#pragma unroll 4
    for (int i = 0; i < 16; i++) {
        int nl = ng * 16 + i;
        const float* xr = xin + (pbase + nl) * 12;
        float acc = bc;
#pragma unroll
        for (int d = 0; d < 12; d++) acc += xr[d] * w[d];
        ushort hh, ll;
        split(acc, hh, ll);
        tile[0][c][nl] = hh;
        tile[1][c][nl] = ll;
    }
    __syncthreads();
    int c2 = t >> 2, ch = t & 3;
#pragma unroll
    for (int pl = 0; pl < 2; pl++) {
        const ushort* s = &tile[pl][c2][ch * 16];
        u16x8 v0 = *(const u16x8*)s;
        u16x8 v1 = *(const u16x8*)(s + 8);
        ushort* dst = xbf + (long)pl * XPLANE + ((long)(b * 256 + m) * 64 + c2) * 256 + n0 + ch * 16;
        *(u16x8*)dst = v0; *(u16x8*)(dst + 8) = v1;
    }
}

// bf16 transpose: xbf_y [b][m][c][n] -> xbf_x [b][n][c][m].
__global__ __launch_bounds__(256) void k_tx(const ushort* __restrict__ src, ushort* __restrict__ dst) {
    __shared__ __align__(16) ushort tl[64][72];
    int t = threadIdx.x;
    int bid = blockIdx.x;
    int ntile = bid & 3, mt = (bid >> 2) & 3, c = (bid >> 4) & 63, b = (bid >> 10) & 3, pl = bid >> 12;
    int m0 = mt * 64, n0 = ntile * 64;
    const ushort* sp = src + (long)pl * XPLANE;
    ushort* dp = dst + (long)pl * XPLANE;
    {
        int row = t >> 2, ch = (t & 3) * 16;
        const ushort* p = sp + ((long)(b * 256 + m0 + row) * 64 + c) * 256 + n0 + ch;
        u16x8 v0 = *(const u16x8*)p;
        u16x8 v1 = *(const u16x8*)(p + 8);
#pragma unroll
        for (int k = 0; k < 8; k++) tl[ch + k][row] = v0[k];
#pragma unroll
        for (int k = 0; k < 8; k++) tl[ch + 8 + k][row] = v1[k];
    }
    __syncthreads();
    {
        int nrow = t >> 2, mch = (t & 3) * 16;
        const ushort* s = &tl[nrow][mch];
        u16x8 v0 = *(const u16x8*)s;
        u16x8 v1 = *(const u16x8*)(s + 8);
        ushort* p = dp + ((long)(b * 256 + n0 + nrow) * 64 + c) * 256 + m0 + mch;
        *(u16x8*)p = v0; *(u16x8*)(p + 8) = v1;
    }
}

// ---------------- fused spectral kernel: DCT -> mix -> iDCT ----------------
__global__ __launch_bounds__(256) void k_spec(const ushort* __restrict__ xbf,
                                              const ushort* __restrict__ Tf,
                                              const ushort* __restrict__ Ttf,
                                              const float* __restrict__ wt,
                                              float* __restrict__ hdst,
                                              long strideA, long strideF, int accum) {
    __shared__ float Xs[32][68];
    __shared__ __align__(16) ushort Xmb[2][64][40];
    int t = threadIdx.x;
    int lane = t & 63, wv = t >> 6, l15 = lane & 15, l4 = lane >> 4;
    int bf = blockIdx.x;
    const ushort* xb = xbf + (long)bf * 16384;

    // ---- DCT (MFMA) ----
    f32x4 a0 = {0.f, 0.f, 0.f, 0.f}, a1 = {0.f, 0.f, 0.f, 0.f};
    int c0 = wv * 16;
#pragma unroll
    for (int ks = 0; ks < 8; ks++) {
        const ushort* bp = xb + (c0 + l15) * 256 + ks * 32 + l4 * 8;
        bfrag bhi = *(const bfrag*)bp;
        bfrag blo = *(const bfrag*)(bp + XPLANE);
        const ushort* ap0 = Tf + (long)((0 * 8 + ks) * 64 + lane) * 8;
        const ushort* ap1 = Tf + (long)((1 * 8 + ks) * 64 + lane) * 8;
        bfrag a0h = *(const bfrag*)ap0, a0l = *(const bfrag*)(ap0 + 8192);
        bfrag a1h = *(const bfrag*)ap1, a1l = *(const bfrag*)(ap1 + 8192);
        a0 = MFMA(a0h, bhi, a0, 0, 0, 0);
        a0 = MFMA(a0h, blo, a0, 0, 0, 0);
        a0 = MFMA(a0l, bhi, a0, 0, 0, 0);
        a1 = MFMA(a1h, bhi, a1, 0, 0, 0);
        a1 = MFMA(a1h, blo, a1, 0, 0, 0);
        a1 = MFMA(a1l, bhi, a1, 0, 0, 0);
    }
#pragma unroll
    for (int r = 0; r < 4; r++) {
        Xs[l4 * 4 + r][c0 + l15] = a0[r];
        Xs[16 + l4 * 4 + r][c0 + l15] = a1[r];
    }
    __syncthreads();

    // ---- mix (VALU, float4-vectorized weights) ----
    {
        int og = t & 15, yq = t >> 4;   // 4 o's per thread, 2 y's per thread
#pragma unroll
        for (int yy = 0; yy < 2; yy++) {
            int y = yq * 2 + yy;
            const float* wb = wt + (long)y * 4096 + og * 4;
            f32x4 a = {0.f, 0.f, 0.f, 0.f};
#pragma unroll 8
            for (int i = 0; i < 64; i++) {
                float xv = Xs[y][i];
                float4 wv = *(const float4*)(wb + i * 64);
                a.x += xv * wv.x; a.y += xv * wv.y; a.z += xv * wv.z; a.w += xv * wv.w;
            }
#pragma unroll
            for (int e = 0; e < 4; e++) {
                ushort hh, ll;
                split(a[e], hh, ll);
                Xmb[0][og * 4 + e][y] = hh;
                Xmb[1][og * 4 + e][y] = ll;
            }
        }
    }
    __syncthreads();

    // ---- iDCT (MFMA) ----
    bfrag vbh[4], vbl[4];
#pragma unroll
    for (int ot = 0; ot < 4; ot++) {
        vbh[ot] = *(const bfrag*)(&Xmb[0][ot * 16 + l15][l4 * 8]);
        vbl[ot] = *(const bfrag*)(&Xmb[1][ot * 16 + l15][l4 * 8]);
    }
    int b = bf >> 8, f = bf & 255;
    float* hb = hdst + (long)b * 4194304 + (long)f * strideF;
#pragma unroll
    for (int ai = 0; ai < 4; ai++) {
        int at = wv * 4 + ai;
        const ushort* ap = Ttf + (long)(at * 64 + lane) * 8;
        bfrag th = *(const bfrag*)ap, tl_ = *(const bfrag*)(ap + 8192);
#pragma unroll
        for (int ot = 0; ot < 4; ot++) {
            f32x4 acc = {0.f, 0.f, 0.f, 0.f};
            acc = MFMA(th, vbh[ot], acc, 0, 0, 0);
            acc = MFMA(th, vbl[ot], acc, 0, 0, 0);
            acc = MFMA(tl_, vbh[ot], acc, 0, 0, 0);
            int arow = at * 16 + l4 * 4;
            float* op = hb + (long)arow * strideA + ot * 16 + l15;
            if (accum) {
#pragma unroll
                for (int r = 0; r < 4; r++) op[(long)r * strideA] += acc[r];
            } else {
#pragma unroll
                for (int r = 0; r < 4; r++) op[(long)r * strideA] = acc[r];
            }
        }
    }
}

// ---------------- FFN via bf16x3 MFMA ----------------
// Block = 64 pixels (one m-row chunk), 256 threads (4 waves); wave wv owns px rows wv*16..+15.
// GEMM1 A-frags read directly from global h (f32 -> hi/lo in-reg).
// As stored in LDS as bf16 hi/lo fragments -> GEMM2 reads frags with zero conversion.
// Residual RMW staged coalesced through LDS.
#define ASW 136   // ushort row stride (128 + 8 pad)
__global__ __launch_bounds__(256) void k_ff(const float* __restrict__ h,
                                            ushort* __restrict__ xbfw,
                                            const ushort* __restrict__ W1hi, const ushort* __restrict__ W1lo,
                                            const float* __restrict__ b1,
                                            const ushort* __restrict__ W2hi, const ushort* __restrict__ W2lo,
                                            const float* __restrict__ b2,
                                            const float* __restrict__ Weff, const float* __restrict__ beff,
                                            float* __restrict__ out, int last) {
    __shared__ __align__(16) ushort Asb[2][64][ASW];   // 34.8 KB
    int t = threadIdx.x;
    int lane = t & 63, wv = t >> 6;
    int l15 = lane & 15, l4 = lane >> 4;
    long p0 = (long)blockIdx.x * 64;

    // GEMM1: A = relu(H @ W1^T + b1)
    f32x4 acc1[8];
#pragma unroll
    for (int nt = 0; nt < 8; nt++) acc1[nt] = (f32x4){0.f, 0.f, 0.f, 0.f};
#pragma unroll
    for (int ks = 0; ks < 2; ks++) {
        const float* hp = h + (p0 + wv * 16 + l15) * 64 + ks * 32 + l4 * 8;
        float4 h0 = *(const float4*)hp;
        float4 h1 = *(const float4*)(hp + 4);
        bfrag ahi, alo;
#pragma unroll
        for (int j = 0; j < 8; j++) {
            float v = (j < 4) ? (&h0.x)[j] : (&h1.x)[j - 4];
            ushort hh, ll;
            split(v, hh, ll);
            ahi[j] = (short)hh; alo[j] = (short)ll;
        }
#pragma unroll
        for (int nt = 0; nt < 8; nt++) {
            long off = (long)((nt * 2 + ks) * 64 + lane) * 8;
            bfrag bhi = *(const bfrag*)(W1hi + off);
            bfrag blo = *(const bfrag*)(W1lo + off);
            acc1[nt] = MFMA(ahi, bhi, acc1[nt], 0, 0, 0);
            acc1[nt] = MFMA(ahi, blo, acc1[nt], 0, 0, 0);
            acc1[nt] = MFMA(alo, bhi, acc1[nt], 0, 0, 0);
        }
    }
    // bias + relu + hi/lo split -> Asb
#pragma unroll
    for (int nt = 0; nt < 8; nt++) {
        float bj = b1[nt * 16 + l15];
        int j = nt * 16 + l15;
#pragma unroll
        for (int r = 0; r < 4; r++) {
            float v = fmaxf(acc1[nt][r] + bj, 0.f);
            int px = wv * 16 + l4 * 4 + r;
            ushort hh, ll;
            split(v, hh, ll);
            Asb[0][px][j] = hh;
            Asb[1][px][j] = ll;
        }
    }
    __syncthreads();

    // GEMM2: O = A @ W2^T  (A-frags straight from LDS, no conversion)
    f32x4 acc2[4];
#pragma unroll
    for (int nt = 0; nt < 4; nt++) acc2[nt] = (f32x4){0.f, 0.f, 0.f, 0.f};
#pragma unroll
    for (int ks = 0; ks < 4; ks++) {
        bfrag ahi = *(const bfrag*)(&Asb[0][wv * 16 + l15][ks * 32 + l4 * 8]);
        bfrag alo = *(const bfrag*)(&Asb[1][wv * 16 + l15][ks * 32 + l4 * 8]);
#pragma unroll
        for (int nt = 0; nt < 4; nt++) {
            long off = (long)((nt * 4 + ks) * 64 + lane) * 8;
            bfrag bhi = *(const bfrag*)(W2hi + off);
            bfrag blo = *(const bfrag*)(W2lo + off);
            acc2[nt] = MFMA(ahi, bhi, acc2[nt], 0, 0, 0);
            acc2[nt] = MFMA(ahi, blo, acc2[nt], 0, 0, 0);
            acc2[nt] = MFMA(alo, bhi, acc2[nt], 0, 0, 0);
        }
    }

    if (last) {
        float be = beff[0];
#pragma unroll
        for (int r = 0; r < 4; r++) {
            float v = 0.f;
#pragma unroll
            for (int nt = 0; nt < 4; nt++) {
                int c = nt * 16 + l15;
                v += (acc2[nt][r] + b2[c]) * Weff[c];
            }
            v += __shfl_xor(v, 1, 64);
            v += __shfl_xor(v, 2, 64);
            v += __shfl_xor(v, 4, 64);
            v += __shfl_xor(v, 8, 64);
            if (l15 == 0) out[p0 + wv * 16 + l4 * 4 + r] = v + be;
        }
    } else {
        __syncthreads();   // Asb fully consumed by GEMM2
        ushort* tile = &Asb[0][0][0];   // reuse as [2][64][72] x-tile (18.4 KB)
        int b = (int)(p0 >> 16), m = (int)((p0 >> 8) & 255), n0 = (int)(p0 & 255);
        int c2 = t >> 2, ch = t & 3;
        // stage residual coalesced into tile
#pragma unroll
        for (int pl = 0; pl < 2; pl++) {
            const ushort* src = xbfw + (long)pl * XPLANE + ((long)(b * 256 + m) * 64 + c2) * 256 + n0 + ch * 16;
            u16x8 v0 = *(const u16x8*)src;
            u16x8 v1 = *(const u16x8*)(src + 8);
            ushort* d = tile + (pl * 64 + c2) * 72 + ch * 16;
            *(u16x8*)d = v0; *(u16x8*)(d + 8) = v1;
        }
        __syncthreads();
        // per-thread RMW in LDS (each (c,nl) owned by exactly one thread)
#pragma unroll
        for (int nt = 0; nt < 4; nt++) {
            int c = nt * 16 + l15;
            float bc = b2[c];
#pragma unroll
            for (int r = 0; r < 4; r++) {
                int nl = wv * 16 + l4 * 4 + r;
                float res = bf2f(tile[(0 * 64 + c) * 72 + nl]) + bf2f(tile[(1 * 64 + c) * 72 + nl]);
                float v = res + acc2[nt][r] + bc;
                ushort hh, ll;
                split(v, hh, ll);
                tile[(0 * 64 + c) * 72 + nl] = hh;
                tile[(1 * 64 + c) * 72 + nl] = ll;
            }
        }
        __syncthreads();
        // coalesced store back to xbf_y
#pragma unroll
        for (int pl = 0; pl < 2; pl++) {
            const ushort* s = tile + (pl * 64 + c2) * 72 + ch * 16;
            u16x8 v0 = *(const u16x8*)s;
            u16x8 v1 = *(const u16x8*)(s + 8);
            ushort* dst = xbfw + (long)pl * XPLANE + ((long)(b * 256 + m) * 64 + c2) * 256 + n0 + ch * 16;
            *(u16x8*)dst = v0; *(u16x8*)(dst + 8) = v1;
        }
    }
}

// ---------------- launcher ----------------

extern "C" void kernel_launch(void* const* d_in, const int* in_sizes, int n_in,
                              void* d_out, int out_size, void* d_ws, size_t ws_size,
                              hipStream_t stream) {
    const float* x_in = (const float*)d_in[0];
    const float* W_in = (const float*)d_in[1];
    const float* b_in = (const float*)d_in[2];
    const float* fw0  = (const float*)d_in[3];
    const float* fw1  = (const float*)d_in[4];
    const float* ffW1 = (const float*)d_in[5];
    const float* ffb1 = (const float*)d_in[6];
    const float* ffW2 = (const float*)d_in[7];
    const float* ffb2 = (const float*)d_in[8];
    const float* W_o1 = (const float*)d_in[9];
    const float* b_o1 = (const float*)d_in[10];
    const float* W_o2 = (const float*)d_in[11];
    const float* b_o2 = (const float*)d_in[12];
    float* out = (float*)d_out;

    // workspace layout: ~196 MiB
    float* ws   = (float*)d_ws;
    float* T    = ws;                     // 8192
    float* w0t  = T + 8192;               // 524288
    float* w1t  = w0t + 524288;           // 524288
    float* Weff = w1t + 524288;           // 64
    float* beff = Weff + 64;              // 64
    float* h    = beff + 64;              // 16777216 (64 MB)
    ushort* Tfrag  = (ushort*)(h + 16777216);   // 16384
    ushort* Ttfrag = Tfrag + 16384;             // 16384
    ushort* W1f_hi = Ttfrag + 16384;            // 32768
    ushort* W1f_lo = W1f_hi + 32768;
    ushort* W2f_hi = W1f_lo + 32768;
    ushort* W2f_lo = W2f_hi + 32768;
    ushort* xbf_y  = W2f_lo + 32768;            // 2*16777216 (64 MB)
    ushort* xbf_x  = xbf_y + 2 * XPLANE;        // 2*16777216 (64 MB)

    k_build_T<<<32, 256, 0, stream>>>(T);
    k_wt<<<2048, 256, 0, stream>>>(fw0, w0t);
    k_wt<<<2048, 256, 0, stream>>>(fw1, w1t);
    k_Tfrag<<<32, 256, 0, stream>>>(T, Tfrag);
    k_Ttfrag<<<32, 256, 0, stream>>>(T, Ttfrag);
    k_wfrag<<<(NLAYERS * HID * CH) / 256, 256, 0, stream>>>(ffW1, W1f_hi, W1f_lo, HID, CH);
    k_wfrag<<<(NLAYERS * CH * HID) / 256, 256, 0, stream>>>(ffW2, W2f_hi, W2f_lo, CH, HID);
    k_head<<<1, 64, 0, stream>>>(W_o1, b_o1, W_o2, b_o2, Weff, beff);
    k_inproj_bf<<<4096, 256, 0, stream>>>(x_in, W_in, b_in, xbf_y);

    for (int l = 0; l < NLAYERS; l++) {
        // y-path: contract n; h[b][m][a=n][c]: strideA=64, strideF(m)=16384; write
        k_spec<<<1024, 256, 0, stream>>>(xbf_y, Tfrag, Ttfrag, w0t + (long)l * 131072,
                                         h, 64L, 16384L, 0);
        // x-path input: xbf_x[b][n][c][m]
        k_tx<<<8192, 256, 0, stream>>>(xbf_y, xbf_x);
        // x-path: contract m; h[b][a=m][f=n][c]: strideA=16384, strideF(n)=64; accumulate
        k_spec<<<1024, 256, 0, stream>>>(xbf_x, Tfrag, Ttfrag, w1t + (long)l * 131072,
                                         h, 16384L, 64L, 1);
        // FFN + residual (RMW on xbf_y) (+ head on last layer)
        k_ff<<<4096, 256, 0, stream>>>(h, xbf_y,
            W1f_hi + (long)l * HID * CH, W1f_lo + (long)l * HID * CH,
            ffb1 + (long)l * HID,
            W2f_hi + (long)l * CH * HID, W2f_lo + (long)l * CH * HID,
            ffb2 + (long)l * CH,
            Weff, beff, out, (l == NLAYERS - 1) ? 1 : 0);
    }
}